// Round 3
// baseline (472.135 us; speedup 1.0000x reference)
//
#include <hip/hip_runtime.h>
#include <math.h>

#define EPS_COS  1e-8f
#define EPS_MASK 1e-16f
#define EPS_SHARP 1e-10f

constexpr int B = 32, N = 8192, M = 128, K = 128;

// ---------------- Kernel 1: cos[b,n] = cosine similarity of keys[b,n,:] vs k[b,:]
// One wave handles TWO rows: lanes 0-31 -> row 2w, lanes 32-63 -> row 2w+1.
// Each lane loads one float4 (32 lanes x 4 floats = 128 = K). 16B/lane coalescing.
__global__ __launch_bounds__(256) void cos_kernel(const float* __restrict__ keys,
                                                  const float* __restrict__ k,
                                                  float* __restrict__ cosv) {
    int wave = (int)((blockIdx.x * blockDim.x + threadIdx.x) >> 6);
    int lane = threadIdx.x & 63;
    int half = lane >> 5;            // 0 or 1: which row of the pair
    int l32  = lane & 31;
    int row  = wave * 2 + half;
    if (row >= B * N) return;
    int b = row >> 13;               // N = 8192

    const float4* krow = (const float4*)(keys + (size_t)row * K);
    const float4* kq   = (const float4*)(k + (size_t)b * K);
    float4 kv = krow[l32];
    float4 qv = kq[l32];
    float dot = kv.x * qv.x + kv.y * qv.y + kv.z * qv.z + kv.w * qv.w;
    float ssk = kv.x * kv.x + kv.y * kv.y + kv.z * kv.z + kv.w * kv.w;
    float ssq = qv.x * qv.x + qv.y * qv.y + qv.z * qv.z + qv.w * qv.w;
#pragma unroll
    for (int off = 16; off > 0; off >>= 1) {   // stays within each 32-lane group
        dot += __shfl_xor(dot, off);
        ssk += __shfl_xor(ssk, off);
        ssq += __shfl_xor(ssq, off);
    }
    if (l32 == 0) {
        float nk = fmaxf(sqrtf(ssk), EPS_COS);
        float nq = fmaxf(sqrtf(ssq), EPS_COS);
        cosv[row] = dot / (nk * nq);
    }
}

// ---------------- Kernel 2: per-batch softmax + top-1 mask + sharpen + r gather
// One block (1024 threads) per batch; 8 elements per thread, kept in registers.
__global__ __launch_bounds__(1024) void weights_kernel(
        const float* __restrict__ cosv, const float* __restrict__ beta,
        const float* __restrict__ gamma, const float* __restrict__ content,
        float* __restrict__ w_out, float* __restrict__ r_out) {
    int b = blockIdx.x;
    int t = threadIdx.x;
    float bet = beta[b];
    float gam = gamma[b];

    float x[8];
#pragma unroll
    for (int i = 0; i < 8; i++) x[i] = bet * cosv[b * N + i * 1024 + t];

    __shared__ float sv[1024];
    __shared__ int   si[1024];

    // ---- 1) max + argmax (lowest index on ties, matching lax.top_k)
    float vmax = x[0];
    int   imax = t;                 // index of x[0] is 0*1024 + t
#pragma unroll
    for (int i = 1; i < 8; i++) {
        int idx = i * 1024 + t;
        if (x[i] > vmax) { vmax = x[i]; imax = idx; }
    }
    sv[t] = vmax; si[t] = imax;
    __syncthreads();
    for (int s = 512; s > 0; s >>= 1) {
        if (t < s) {
            float ov = sv[t + s]; int oi = si[t + s];
            if (ov > sv[t] || (ov == sv[t] && oi < si[t])) { sv[t] = ov; si[t] = oi; }
        }
        __syncthreads();
    }
    float gmax = sv[0];
    int   gidx = si[0];
    __syncthreads();

    // ---- 2) softmax denominator
    float e[8];
    float lsum = 0.f;
#pragma unroll
    for (int i = 0; i < 8; i++) { e[i] = expf(x[i] - gmax); lsum += e[i]; }
    sv[t] = lsum;
    __syncthreads();
    for (int s = 512; s > 0; s >>= 1) {
        if (t < s) sv[t] += sv[t + s];
        __syncthreads();
    }
    float denom = sv[0];
    __syncthreads();

    // ---- 3) masked sum: sum(wc * mask)
    float wcm[8];
    float lm = 0.f;
#pragma unroll
    for (int i = 0; i < 8; i++) {
        int idx = i * 1024 + t;
        float wc = e[i] / denom;
        float m  = (idx == gidx) ? 1.0f : EPS_MASK;
        wcm[i] = wc * m;
        lm += wcm[i];
    }
    sv[t] = lm;
    __syncthreads();
    for (int s = 512; s > 0; s >>= 1) {
        if (t < s) sv[t] += sv[t + s];
        __syncthreads();
    }
    float sumM = sv[0];
    __syncthreads();

    // ---- 4) sharpen: p = (wc_norm + eps)^gamma, normalize
    float p[8];
    float lp = 0.f;
#pragma unroll
    for (int i = 0; i < 8; i++) {
        p[i] = powf(wcm[i] / sumM + EPS_SHARP, gam);
        lp += p[i];
    }
    sv[t] = lp;
    __syncthreads();
    for (int s = 512; s > 0; s >>= 1) {
        if (t < s) sv[t] += sv[t + s];
        __syncthreads();
    }
    float wden = sv[0] + EPS_SHARP;

#pragma unroll
    for (int i = 0; i < 8; i++) w_out[b * N + i * 1024 + t] = p[i] / wden;

    // ---- r gather: content[b, gidx, :]
    if (t < M) r_out[b * M + t] = content[((size_t)b * N + gidx) * M + t];
}

// ---------------- Kernel 3: rank-1 interpolation update (the big elementwise pass)
// Grid-stride over float4 elements; one float4 of content + one of keys per step.
__global__ __launch_bounds__(256) void update_kernel(
        const float* __restrict__ content, const float* __restrict__ keys,
        const float* __restrict__ a, const float* __restrict__ a_k,
        const float* __restrict__ w,
        float* __restrict__ nc, float* __restrict__ nk) {
    const size_t total = (size_t)B * N * M / 4;          // float4 count
    const size_t stride = (size_t)gridDim.x * blockDim.x;
    const float4* c4  = (const float4*)content;
    const float4* k4  = (const float4*)keys;
    const float4* a4  = (const float4*)a;
    const float4* ak4 = (const float4*)a_k;

    for (size_t e = (size_t)blockIdx.x * blockDim.x + threadIdx.x;
         e < total; e += stride) {
        int b  = (int)(e >> 18);           // N*M/4 = 262144
        int n  = (int)((e >> 5) & 8191);   // M/4 = 32
        int m4 = (int)(e & 31);

        float ww = w[(b << 13) + n];       // issue scalar load first
        float4 cv  = c4[e];
        float4 kv  = k4[e];
        float4 av  = a4[(b << 5) + m4];
        float4 akv = ak4[(b << 5) + m4];

        float4 o1;
        o1.x = cv.x + ww * (av.x - cv.x);
        o1.y = cv.y + ww * (av.y - cv.y);
        o1.z = cv.z + ww * (av.z - cv.z);
        o1.w = cv.w + ww * (av.w - cv.w);
        ((float4*)nc)[e] = o1;

        float4 o2;
        o2.x = kv.x + ww * (akv.x - kv.x);
        o2.y = kv.y + ww * (akv.y - kv.y);
        o2.z = kv.z + ww * (akv.z - kv.z);
        o2.w = kv.w + ww * (akv.w - kv.w);
        ((float4*)nk)[e] = o2;
    }
}

extern "C" void kernel_launch(void* const* d_in, const int* in_sizes, int n_in,
                              void* d_out, int out_size, void* d_ws, size_t ws_size,
                              hipStream_t stream) {
    const float* content = (const float*)d_in[0];
    const float* keys    = (const float*)d_in[1];
    const float* k       = (const float*)d_in[2];
    const float* beta    = (const float*)d_in[3];
    const float* gamma   = (const float*)d_in[4];
    const float* a_k     = (const float*)d_in[5];
    const float* a       = (const float*)d_in[6];

    float* out   = (float*)d_out;
    float* w_out = out;                              // [B,N]
    float* r_out = out + (size_t)B * N;              // [B,M]
    float* nc    = r_out + (size_t)B * M;            // [B,N,M]
    float* nk    = nc + (size_t)B * N * M;           // [B,N,K]

    float* cosv = (float*)d_ws;                      // [B,N] scratch

    // 1) cosine similarities: 4 waves/block, 2 rows per wave
    cos_kernel<<<(B * N / 2 + 3) / 4, 256, 0, stream>>>(keys, k, cosv);

    // 2) per-batch softmax/top-1/sharpen + r gather
    weights_kernel<<<B, 1024, 0, stream>>>(cosv, beta, gamma, content, w_out, r_out);

    // 3) big elementwise update, grid-stride with 2048 blocks
    update_kernel<<<2048, 256, 0, stream>>>(content, keys, a, a_k, w_out, nc, nk);
}

// Round 4
// 464.706 us; speedup vs baseline: 1.0160x; 1.0160x over previous
//
#include <hip/hip_runtime.h>
#include <math.h>

#define EPS_COS  1e-8f
#define EPS_MASK 1e-16f
#define EPS_SHARP 1e-10f

constexpr int B = 32, N = 8192, M = 128, K = 128;

typedef float v4f __attribute__((ext_vector_type(4)));

// ---------------- Kernel 1: cos[b,n] = cosine similarity of keys[b,n,:] vs k[b,:]
// One wave handles TWO rows: lanes 0-31 -> row 2w, lanes 32-63 -> row 2w+1.
// Each lane loads one float4 (32 lanes x 4 floats = 128 = K). 16B/lane coalescing.
// NOTE: keys loaded with a PLAIN load on purpose — warms L3 for update_kernel.
__global__ __launch_bounds__(256) void cos_kernel(const float* __restrict__ keys,
                                                  const float* __restrict__ k,
                                                  float* __restrict__ cosv) {
    int wave = (int)((blockIdx.x * blockDim.x + threadIdx.x) >> 6);
    int lane = threadIdx.x & 63;
    int half = lane >> 5;            // 0 or 1: which row of the pair
    int l32  = lane & 31;
    int row  = wave * 2 + half;
    if (row >= B * N) return;
    int b = row >> 13;               // N = 8192

    const v4f* krow = (const v4f*)(keys + (size_t)row * K);
    const v4f* kq   = (const v4f*)(k + (size_t)b * K);
    v4f kv = krow[l32];
    v4f qv = kq[l32];
    float dot = kv.x * qv.x + kv.y * qv.y + kv.z * qv.z + kv.w * qv.w;
    float ssk = kv.x * kv.x + kv.y * kv.y + kv.z * kv.z + kv.w * kv.w;
    float ssq = qv.x * qv.x + qv.y * qv.y + qv.z * qv.z + qv.w * qv.w;
#pragma unroll
    for (int off = 16; off > 0; off >>= 1) {   // stays within each 32-lane group
        dot += __shfl_xor(dot, off);
        ssk += __shfl_xor(ssk, off);
        ssq += __shfl_xor(ssq, off);
    }
    if (l32 == 0) {
        float nk = fmaxf(sqrtf(ssk), EPS_COS);
        float nq = fmaxf(sqrtf(ssq), EPS_COS);
        cosv[row] = dot / (nk * nq);
    }
}

// ---------------- Kernel 2: per-batch softmax + top-1 mask + sharpen + r gather
// One block (1024 threads) per batch; 8 elements per thread, kept in registers.
// (Unchanged this round — isolating the K3 experiment.)
__global__ __launch_bounds__(1024) void weights_kernel(
        const float* __restrict__ cosv, const float* __restrict__ beta,
        const float* __restrict__ gamma, const float* __restrict__ content,
        float* __restrict__ w_out, float* __restrict__ r_out) {
    int b = blockIdx.x;
    int t = threadIdx.x;
    float bet = beta[b];
    float gam = gamma[b];

    float x[8];
#pragma unroll
    for (int i = 0; i < 8; i++) x[i] = bet * cosv[b * N + i * 1024 + t];

    __shared__ float sv[1024];
    __shared__ int   si[1024];

    // ---- 1) max + argmax (lowest index on ties, matching lax.top_k)
    float vmax = x[0];
    int   imax = t;                 // index of x[0] is 0*1024 + t
#pragma unroll
    for (int i = 1; i < 8; i++) {
        int idx = i * 1024 + t;
        if (x[i] > vmax) { vmax = x[i]; imax = idx; }
    }
    sv[t] = vmax; si[t] = imax;
    __syncthreads();
    for (int s = 512; s > 0; s >>= 1) {
        if (t < s) {
            float ov = sv[t + s]; int oi = si[t + s];
            if (ov > sv[t] || (ov == sv[t] && oi < si[t])) { sv[t] = ov; si[t] = oi; }
        }
        __syncthreads();
    }
    float gmax = sv[0];
    int   gidx = si[0];
    __syncthreads();

    // ---- 2) softmax denominator
    float e[8];
    float lsum = 0.f;
#pragma unroll
    for (int i = 0; i < 8; i++) { e[i] = expf(x[i] - gmax); lsum += e[i]; }
    sv[t] = lsum;
    __syncthreads();
    for (int s = 512; s > 0; s >>= 1) {
        if (t < s) sv[t] += sv[t + s];
        __syncthreads();
    }
    float denom = sv[0];
    __syncthreads();

    // ---- 3) masked sum: sum(wc * mask)
    float wcm[8];
    float lm = 0.f;
#pragma unroll
    for (int i = 0; i < 8; i++) {
        int idx = i * 1024 + t;
        float wc = e[i] / denom;
        float m  = (idx == gidx) ? 1.0f : EPS_MASK;
        wcm[i] = wc * m;
        lm += wcm[i];
    }
    sv[t] = lm;
    __syncthreads();
    for (int s = 512; s > 0; s >>= 1) {
        if (t < s) sv[t] += sv[t + s];
        __syncthreads();
    }
    float sumM = sv[0];
    __syncthreads();

    // ---- 4) sharpen: p = (wc_norm + eps)^gamma, normalize
    float p[8];
    float lp = 0.f;
#pragma unroll
    for (int i = 0; i < 8; i++) {
        p[i] = powf(wcm[i] / sumM + EPS_SHARP, gam);
        lp += p[i];
    }
    sv[t] = lp;
    __syncthreads();
    for (int s = 512; s > 0; s >>= 1) {
        if (t < s) sv[t] += sv[t + s];
        __syncthreads();
    }
    float wden = sv[0] + EPS_SHARP;

#pragma unroll
    for (int i = 0; i < 8; i++) w_out[b * N + i * 1024 + t] = p[i] / wden;

    // ---- r gather: content[b, gidx, :]
    if (t < M) r_out[b * M + t] = content[((size_t)b * N + gidx) * M + t];
}

// ---------------- Kernel 3: rank-1 interpolation update (the big elementwise pass)
// Streaming discipline: content = nt-load (read-once), nc/nk = nt-store (no L3
// pollution), keys = PLAIN load (hope: Infinity-Cache hit, warmed by cos_kernel).
__global__ __launch_bounds__(256) void update_kernel(
        const float* __restrict__ content, const float* __restrict__ keys,
        const float* __restrict__ a, const float* __restrict__ a_k,
        const float* __restrict__ w,
        float* __restrict__ nc, float* __restrict__ nk) {
    const size_t total = (size_t)B * N * M / 4;          // float4 count
    const size_t stride = (size_t)gridDim.x * blockDim.x;
    const v4f* c4  = (const v4f*)content;
    const v4f* k4  = (const v4f*)keys;
    const v4f* a4  = (const v4f*)a;
    const v4f* ak4 = (const v4f*)a_k;
    v4f* nc4 = (v4f*)nc;
    v4f* nk4 = (v4f*)nk;

    for (size_t e = (size_t)blockIdx.x * blockDim.x + threadIdx.x;
         e < total; e += stride) {
        int b  = (int)(e >> 18);           // N*M/4 = 262144
        int n  = (int)((e >> 5) & 8191);   // M/4 = 32
        int m4 = (int)(e & 31);

        float ww = w[(b << 13) + n];               // broadcast within 32 lanes
        v4f kv  = k4[e];                           // plain: L3 hit expected
        v4f cv  = __builtin_nontemporal_load(&c4[e]);  // streaming read-once
        v4f av  = a4[(b << 5) + m4];               // L1-resident
        v4f akv = ak4[(b << 5) + m4];              // L1-resident

        v4f o1 = cv + ww * (av - cv);
        v4f o2 = kv + ww * (akv - kv);
        __builtin_nontemporal_store(o1, &nc4[e]);
        __builtin_nontemporal_store(o2, &nk4[e]);
    }
}

extern "C" void kernel_launch(void* const* d_in, const int* in_sizes, int n_in,
                              void* d_out, int out_size, void* d_ws, size_t ws_size,
                              hipStream_t stream) {
    const float* content = (const float*)d_in[0];
    const float* keys    = (const float*)d_in[1];
    const float* k       = (const float*)d_in[2];
    const float* beta    = (const float*)d_in[3];
    const float* gamma   = (const float*)d_in[4];
    const float* a_k     = (const float*)d_in[5];
    const float* a       = (const float*)d_in[6];

    float* out   = (float*)d_out;
    float* w_out = out;                              // [B,N]
    float* r_out = out + (size_t)B * N;              // [B,M]
    float* nc    = r_out + (size_t)B * M;            // [B,N,M]
    float* nk    = nc + (size_t)B * N * M;           // [B,N,K]

    float* cosv = (float*)d_ws;                      // [B,N] scratch

    // 1) cosine similarities: 4 waves/block, 2 rows per wave
    cos_kernel<<<(B * N / 2 + 3) / 4, 256, 0, stream>>>(keys, k, cosv);

    // 2) per-batch softmax/top-1/sharpen + r gather
    weights_kernel<<<B, 1024, 0, stream>>>(cosv, beta, gamma, content, w_out, r_out);

    // 3) big elementwise update, grid-stride with 2048 blocks
    update_kernel<<<2048, 256, 0, stream>>>(content, keys, a, a_k, w_out, nc, nk);
}